// Round 8
// baseline (29.464 us; speedup 1.0000x reference)
//
#include <hip/hip_runtime.h>
#include <math.h>

// Problem shape (fixed by setup_inputs): B=4, N=M=4096, D=3, fp32.
#define BATCH 4
#define NPTS  4096
#define RPB   256                 // threads per block
#define ROWS  4                   // rows (X points) per thread
#define ROWS_PER_BLOCK (RPB * ROWS)          // 1024
#define CHUNKS (NPTS / ROWS_PER_BLOCK)       // 4 row-chunks
#define SEGS  32                  // m-split -> 4*32*4*2 = 1024 blocks (4/CU)
#define SEG_LEN (NPTS / SEGS)     // 128 Y points staged per block

#define RED_BLOCKS 128            // kernel-2 grid (128*256 = 32768 = one thread/row)
#define FP_SCALE   268435456.0    // 2^28 fixed-point scale for deterministic sum

// ws layout: [0..8) u64 fixed-point total | [8..12) u32 arrival counter |
//            [64 ..) float part[2][BATCH][SEGS][NPTS]  (4 MB)

// R3 structure (empirical optimum of the grid sweep: 1024 blocks = 4/CU),
// single delta: paired j-loop -> v_min3_f32, 3.5 ops/pair instead of 7.
__global__ __launch_bounds__(RPB) void ahd_min_kernel(
    const float* __restrict__ set1, const float* __restrict__ set2,
    float* __restrict__ part, unsigned long long* __restrict__ total,
    unsigned int* __restrict__ counter)
{
    // One designated thread re-inits kernel-2's accumulators every call
    // (kernel boundary orders this before any kernel-2 read).
    if (blockIdx.x == 0 && blockIdx.y == 0 && blockIdx.z == 0 && threadIdx.x == 0) {
        *total = 0ULL;
        *counter = 0u;
    }

    const int dir      = blockIdx.z;
    const int b        = blockIdx.y;
    const int rowChunk = blockIdx.x / SEGS;
    const int seg      = blockIdx.x % SEGS;

    const float* __restrict__ X = dir ? set2 : set1;
    const float* __restrict__ Y = dir ? set1 : set2;

    __shared__ float4 ys[SEG_LEN];   // {y0, y1, y2, |y|^2}

    const float* ybase = Y + ((size_t)b * NPTS + (size_t)seg * SEG_LEN) * 3;
    for (int i = threadIdx.x; i < SEG_LEN; i += RPB) {
        const float y0 = ybase[i * 3 + 0];
        const float y1 = ybase[i * 3 + 1];
        const float y2 = ybase[i * 3 + 2];
        ys[i] = make_float4(y0, y1, y2, fmaf(y0, y0, fmaf(y1, y1, y2 * y2)));
    }
    __syncthreads();

    float nx0[ROWS], nx1[ROWS], nx2[ROWS], hx[ROWS], acc[ROWS];
    const int rowBase = rowChunk * ROWS_PER_BLOCK + threadIdx.x;
    #pragma unroll
    for (int r = 0; r < ROWS; ++r) {
        const float* xp = X + ((size_t)b * NPTS + rowBase + r * RPB) * 3;
        const float x0 = xp[0], x1 = xp[1], x2 = xp[2];
        nx0[r] = -2.0f * x0;
        nx1[r] = -2.0f * x1;
        nx2[r] = -2.0f * x2;
        hx[r]  = fmaf(x0, x0, fmaf(x1, x1, x2 * x2));
        acc[r] = 3.4e38f;
    }

    // Paired j-loop: fminf(acc, fminf(qa,qb)) -> v_min3_f32 (3.5 ops/pair).
    // unroll 4 => 8 broadcast ds_read_b128 in flight per lgkmcnt wait,
    // 112 VALU ops between waits. 4 independent min chains.
    #pragma unroll 4
    for (int j = 0; j < SEG_LEN; j += 2) {
        const float4 ya = ys[j];       // broadcast reads, conflict-free
        const float4 yb = ys[j + 1];
        #pragma unroll
        for (int r = 0; r < ROWS; ++r) {
            const float qa = fmaf(nx0[r], ya.x,
                             fmaf(nx1[r], ya.y,
                             fmaf(nx2[r], ya.z, ya.w)));
            const float qb = fmaf(nx0[r], yb.x,
                             fmaf(nx1[r], yb.y,
                             fmaf(nx2[r], yb.z, yb.w)));
            acc[r] = fminf(acc[r], fminf(qa, qb));
        }
    }

    // partial d^2 for this segment, clamped >= 0; coalesced plain stores
    float* dst = part + (((size_t)(dir * BATCH + b) * SEGS + seg) * NPTS);
    #pragma unroll
    for (int r = 0; r < ROWS; ++r)
        dst[rowBase + r * RPB] = fmaxf(acc[r] + hx[r], 0.0f);
}

// Kernel 2: per row min over SEGS partials, sqrt, deterministic fixed-point
// sum via one u64 atomic; last-arriving block finalizes out[0].
__global__ __launch_bounds__(RPB) void ahd_reduce_kernel(
    const float* __restrict__ part, unsigned long long* __restrict__ total,
    unsigned int* __restrict__ counter, float* __restrict__ out)
{
    const int g    = blockIdx.x * RPB + threadIdx.x;   // 0..32767
    const int dirb = g >> 12;                          // which [dir][b] plane
    const int n    = g & (NPTS - 1);

    const float* p = part + ((size_t)dirb * SEGS) * NPTS + n;
    float m = p[0];
    #pragma unroll 8
    for (int s = 1; s < SEGS; ++s)
        m = fminf(m, p[(size_t)s * NPTS]);             // coalesced per seg

    float d = sqrtf(m);

    // wave tree-sum (deterministic order)
    #pragma unroll
    for (int off = 32; off > 0; off >>= 1)
        d += __shfl_down(d, off, 64);

    __shared__ unsigned long long ws[4];
    const int lane = threadIdx.x & 63;
    const int w    = threadIdx.x >> 6;
    if (lane == 0)
        ws[w] = (unsigned long long)((double)d * FP_SCALE);
    __syncthreads();

    if (threadIdx.x == 0) {
        const unsigned long long bs = ws[0] + ws[1] + ws[2] + ws[3];
        atomicAdd(total, bs);
        __threadfence();
        const unsigned int cnt = atomicAdd(counter, 1u);
        if (cnt == (unsigned int)(gridDim.x - 1)) {
            // last arriver: all total-adds are visible (fence + counter order)
            const unsigned long long fin = atomicAdd(total, 0ULL);
            out[0] = (float)((double)fin * (1.0 / FP_SCALE)
                             * (1.0 / (double)(BATCH * NPTS)));
        }
    }
}

extern "C" void kernel_launch(void* const* d_in, const int* in_sizes, int n_in,
                              void* d_out, int out_size, void* d_ws, size_t ws_size,
                              hipStream_t stream) {
    const float* set1 = (const float*)d_in[0];
    const float* set2 = (const float*)d_in[1];
    float* out = (float*)d_out;

    unsigned long long* total = (unsigned long long*)d_ws;
    unsigned int* counter = (unsigned int*)((char*)d_ws + 8);
    float* part = (float*)((char*)d_ws + 64);   // 2*BATCH*SEGS*NPTS floats = 4 MB

    dim3 grid(CHUNKS * SEGS, BATCH, 2);
    ahd_min_kernel<<<grid, dim3(RPB), 0, stream>>>(set1, set2, part, total, counter);
    ahd_reduce_kernel<<<RED_BLOCKS, dim3(RPB), 0, stream>>>(part, total, counter, out);
}

// Round 9
// 24.689 us; speedup vs baseline: 1.1934x; 1.1934x over previous
//
#include <hip/hip_runtime.h>
#include <math.h>

// Problem shape (fixed by setup_inputs): B=4, N=M=4096, D=3, fp32.
#define BATCH 4
#define NPTS  4096
#define RPB   256                 // threads per block
#define ROWS  4                   // rows (X points) per thread
#define ROWS_PER_BLOCK (RPB * ROWS)          // 1024
#define CHUNKS (NPTS / ROWS_PER_BLOCK)       // 4 row-chunks
#define SEGS  32                  // m-split -> 4*32*4*2 = 1024 blocks (4/CU)
#define SEG_LEN (NPTS / SEGS)     // 128 Y points staged per block

#define NMINS (2 * BATCH * NPTS)  // 32768 per-row min slots
#define FP_SCALE 268435456.0      // 2^28 fixed-point scale for deterministic sum

// ws layout: [0..8) u64 fixed-point total | [8..12) u32 arrival counter |
//            [64 ..) u32 mins[2][BATCH][NPTS]  (128 KB, f32-as-uint d^2)

// Init: mins <- 0xFFFFFFFF (uint max == +inf for uint-ordered non-neg f32),
// total/counter <- 0. 32 blocks x 256 threads x 1 uint4 store covers 128 KB.
__global__ __launch_bounds__(RPB) void ahd_init(
    uint4* __restrict__ mins4, unsigned long long* __restrict__ total,
    unsigned int* __restrict__ counter)
{
    const int i = blockIdx.x * RPB + threadIdx.x;
    mins4[i] = make_uint4(0xFFFFFFFFu, 0xFFFFFFFFu, 0xFFFFFFFFu, 0xFFFFFFFFu);
    if (i == 0) { *total = 0ULL; *counter = 0u; }
}

// R3's min kernel verbatim (1024 blocks = 4/CU, simple 4-op/pair loop, the
// empirical optimum of the R1-R8 sweep); only the epilogue changed:
// uint atomicMin into the 128 KB mins buffer instead of 4 MB partials.
__global__ __launch_bounds__(RPB) void ahd_min_kernel(
    const float* __restrict__ set1, const float* __restrict__ set2,
    unsigned int* __restrict__ mins)
{
    const int dir      = blockIdx.z;
    const int b        = blockIdx.y;
    const int rowChunk = blockIdx.x / SEGS;
    const int seg      = blockIdx.x % SEGS;

    const float* __restrict__ X = dir ? set2 : set1;
    const float* __restrict__ Y = dir ? set1 : set2;

    __shared__ float4 ys[SEG_LEN];   // {y0, y1, y2, |y|^2}

    const float* ybase = Y + ((size_t)b * NPTS + (size_t)seg * SEG_LEN) * 3;
    for (int i = threadIdx.x; i < SEG_LEN; i += RPB) {
        const float y0 = ybase[i * 3 + 0];
        const float y1 = ybase[i * 3 + 1];
        const float y2 = ybase[i * 3 + 2];
        ys[i] = make_float4(y0, y1, y2, fmaf(y0, y0, fmaf(y1, y1, y2 * y2)));
    }
    __syncthreads();

    float nx0[ROWS], nx1[ROWS], nx2[ROWS], hx[ROWS], acc[ROWS];
    const int rowBase = rowChunk * ROWS_PER_BLOCK + threadIdx.x;
    #pragma unroll
    for (int r = 0; r < ROWS; ++r) {
        const float* xp = X + ((size_t)b * NPTS + rowBase + r * RPB) * 3;
        const float x0 = xp[0], x1 = xp[1], x2 = xp[2];
        nx0[r] = -2.0f * x0;
        nx1[r] = -2.0f * x1;
        nx2[r] = -2.0f * x2;
        hx[r]  = fmaf(x0, x0, fmaf(x1, x1, x2 * x2));
        acc[r] = 3.4e38f;
    }

    // Simple j-loop (R3): 3 FMA + 1 fmin per pair, 4 independent min chains,
    // broadcast ds_read_b128 conflict-free, unroll 8.
    #pragma unroll 8
    for (int j = 0; j < SEG_LEN; ++j) {
        const float4 y = ys[j];
        #pragma unroll
        for (int r = 0; r < ROWS; ++r) {
            const float q = fmaf(nx0[r], y.x,
                            fmaf(nx1[r], y.y,
                            fmaf(nx2[r], y.z, y.w)));
            acc[r] = fminf(acc[r], q);
        }
    }

    // d^2 clamped >= 0 so uint bit-pattern ordering holds; fire-and-forget
    // atomicMin (order-independent and exact -> deterministic).
    unsigned int* base = mins + (size_t)dir * BATCH * NPTS + (size_t)b * NPTS;
    #pragma unroll
    for (int r = 0; r < ROWS; ++r) {
        const float d2 = fmaxf(acc[r] + hx[r], 0.0f);
        atomicMin(&base[rowBase + r * RPB], __float_as_uint(d2));
    }
}

// Kernel 3: 32 blocks x 256 threads; one uint4 (4 rows) per thread ->
// sqrt, wave tree-sum, one u64 fixed-point atomic per block; last-arriving
// block finalizes out[0].
__global__ __launch_bounds__(RPB) void ahd_reduce_kernel(
    const uint4* __restrict__ mins4, unsigned long long* __restrict__ total,
    unsigned int* __restrict__ counter, float* __restrict__ out)
{
    const int i = blockIdx.x * RPB + threadIdx.x;   // 0..8191
    const uint4 v = mins4[i];
    float d = sqrtf(__uint_as_float(v.x)) + sqrtf(__uint_as_float(v.y))
            + sqrtf(__uint_as_float(v.z)) + sqrtf(__uint_as_float(v.w));

    // wave tree-sum (deterministic order)
    #pragma unroll
    for (int off = 32; off > 0; off >>= 1)
        d += __shfl_down(d, off, 64);

    __shared__ unsigned long long ws[4];
    const int lane = threadIdx.x & 63;
    const int w    = threadIdx.x >> 6;
    if (lane == 0)
        ws[w] = (unsigned long long)((double)d * FP_SCALE);
    __syncthreads();

    if (threadIdx.x == 0) {
        const unsigned long long bs = ws[0] + ws[1] + ws[2] + ws[3];
        atomicAdd(total, bs);
        __threadfence();
        const unsigned int cnt = atomicAdd(counter, 1u);
        if (cnt == (unsigned int)(gridDim.x - 1)) {
            // last arriver: all total-adds are visible (fence + counter order)
            const unsigned long long fin = atomicAdd(total, 0ULL);
            out[0] = (float)((double)fin * (1.0 / FP_SCALE)
                             * (1.0 / (double)(BATCH * NPTS)));
        }
    }
}

extern "C" void kernel_launch(void* const* d_in, const int* in_sizes, int n_in,
                              void* d_out, int out_size, void* d_ws, size_t ws_size,
                              hipStream_t stream) {
    const float* set1 = (const float*)d_in[0];
    const float* set2 = (const float*)d_in[1];
    float* out = (float*)d_out;

    unsigned long long* total = (unsigned long long*)d_ws;
    unsigned int* counter = (unsigned int*)((char*)d_ws + 8);
    unsigned int* mins = (unsigned int*)((char*)d_ws + 64);   // 128 KB

    ahd_init<<<NMINS / (4 * RPB), dim3(RPB), 0, stream>>>(
        (uint4*)mins, total, counter);
    dim3 grid(CHUNKS * SEGS, BATCH, 2);
    ahd_min_kernel<<<grid, dim3(RPB), 0, stream>>>(set1, set2, mins);
    ahd_reduce_kernel<<<NMINS / (4 * RPB), dim3(RPB), 0, stream>>>(
        (const uint4*)mins, total, counter, out);
}